// Round 5
// baseline (620.049 us; speedup 1.0000x reference)
//
#include <hip/hip_runtime.h>
#include <hip/hip_cooperative_groups.h>

namespace cg = cooperative_groups;

#define N_NODES 10000
#define N_EDGES 640000
#define D       128

#define HB          64                    // hist chunks (one block each)
#define GEMM_BLOCKS 313                   // ceil(10000/32)
#define WORK_BLOCKS (HB + GEMM_BLOCKS)    // 377 blocks active in phase 1
#define NBLK        768                   // 3 blocks/CU x 256 CU (LDS: 3x40KB=120KB/CU ok)
#define NTHR        (NBLK * 256)          // 196608 threads: phases 2-4 single-round
#define CHUNK       10000                 // edges per hist chunk
#define PAD         256                   // padded CSR bucket

// pack two fp32 -> two bf16 (RNE) in one uint (low = a, high = b)
__device__ inline unsigned bf16pair(float a, float b) {
    unsigned ua = __float_as_uint(a), ub = __float_as_uint(b);
    ua = (ua + 0x7fffu + ((ua >> 16) & 1u)) >> 16;
    ub = (ub + 0x7fffu + ((ub >> 16) & 1u)) >> 16;
    return ua | (ub << 16);
}

union FusedSmem {
    float As[32][132];    // gemm A-tile (16.9 KB)
    int   cnt[N_NODES];   // hist counters (40 KB)
};

__device__ inline void acc8(float* acc, uint4 v) {
    acc[0] += __uint_as_float(v.x << 16);
    acc[1] += __uint_as_float(v.x & 0xffff0000u);
    acc[2] += __uint_as_float(v.y << 16);
    acc[3] += __uint_as_float(v.y & 0xffff0000u);
    acc[4] += __uint_as_float(v.z << 16);
    acc[5] += __uint_as_float(v.z & 0xffff0000u);
    acc[6] += __uint_as_float(v.w << 16);
    acc[7] += __uint_as_float(v.w & 0xffff0000u);
}

// ---------------------------------------------------------------------------
// Cooperative mega-kernel: all 4 phases in one dispatch.
// R4 post-mortem: plain-launch spin barrier deadlocked (residency not
// guaranteed without cooperative launch) + Y-store index bug (tx*2 vs tx).
// Both fixed: hipLaunchCooperativeKernel + grid.sync(), verified index.
// 768 blocks: 377 work phase 1, all 768 make phases 2-4 single-round.
// ---------------------------------------------------------------------------
__global__ __launch_bounds__(256, 3) void mega_kernel(
    const float* __restrict__ nodes, const float* __restrict__ Wm,
    const int* __restrict__ senders, const int* __restrict__ receivers,
    const float* __restrict__ bias, float* __restrict__ out,
    unsigned* __restrict__ Yb, unsigned* __restrict__ pack,
    int* __restrict__ bcnt, int* __restrict__ deg,
    int* __restrict__ csr)
{
    cg::grid_group grid = cg::this_grid();
    __shared__ FusedSmem sm;
    const int t   = threadIdx.x;
    const int bid = blockIdx.x;

    // ---------------- phase 1: hist (0..63) || GEMM (64..376) || idle rest
    if (bid < HB) {
        const int b = bid;
        for (int n = t; n < N_NODES; n += 256) sm.cnt[n] = 0;
        __syncthreads();
        const int base = b * CHUNK;
        for (int i = t; i < CHUNK; i += 256) {
            int r = receivers[base + i];
            int s = senders[base + i];
            int l = atomicAdd(&sm.cnt[r], 1);          // LDS atomic: ns-latency
            pack[base + i] = (unsigned)s | ((unsigned)r << 14) | ((unsigned)l << 28);
        }
        __syncthreads();
        int* dst = bcnt + b * N_NODES;
        for (int n = t; n < N_NODES; n += 256) dst[n] = sm.cnt[n];
    } else if (bid < WORK_BLOCKS) {
        const int row0 = (bid - HB) * 32;

        for (int i = t; i < 1024; i += 256) {
            int r  = i >> 5;
            int c  = i & 31;
            int gr = row0 + r;
            float4 v = make_float4(0.f, 0.f, 0.f, 0.f);
            if (gr < N_NODES) v = ((const float4*)nodes)[gr * 32 + c];
            *((float4*)&sm.As[r][c * 4]) = v;
        }
        __syncthreads();

        const int tx = t & 15;
        const int ty = t >> 4;
        const int r0 = ty * 2;

        float acc[2][8];
#pragma unroll
        for (int i = 0; i < 2; i++)
#pragma unroll
            for (int j = 0; j < 8; j++) acc[i][j] = 0.f;

        const float4* W4 = (const float4*)Wm;
#pragma unroll 4
        for (int k = 0; k < 128; k++) {
            float  a0 = sm.As[r0][k];
            float  a1 = sm.As[r0 + 1][k];
            float4 w0 = W4[k * 32 + tx * 2];
            float4 w1 = W4[k * 32 + tx * 2 + 1];
            float  wv[8] = {w0.x, w0.y, w0.z, w0.w, w1.x, w1.y, w1.z, w1.w};
#pragma unroll
            for (int j = 0; j < 8; j++) {
                acc[0][j] += a0 * wv[j];
                acc[1][j] += a1 * wv[j];
            }
        }

#pragma unroll
        for (int i = 0; i < 2; i++) {
            int gr = row0 + r0 + i;
            if (gr < N_NODES) {
                uint4 o;
                o.x = bf16pair(acc[i][0], acc[i][1]);
                o.y = bf16pair(acc[i][2], acc[i][3]);
                o.z = bf16pair(acc[i][4], acc[i][5]);
                o.w = bf16pair(acc[i][6], acc[i][7]);
                ((uint4*)Yb)[gr * 16 + tx] = o;        // 16 uint4 per 128-bf16 row
            }
        }
    }

    __threadfence();
    grid.sync();

    // ---------------- phase 2: column scan (4 threads/node, shfl combine)
    {
        const int g = bid * 256 + t;                   // 40000 < NTHR: single round
        const int n = g >> 2;
        const int q = g & 3;
        if (n < N_NODES) {
            int pre[16];
            int s = 0;
#pragma unroll
            for (int j = 0; j < 16; j++) {
                int v = bcnt[(q * 16 + j) * N_NODES + n];
                pre[j] = s;
                s += v;
            }
            const int lane = t & 63;
            const int gb   = lane & ~3;
            int s0 = __shfl(s, gb + 0);
            int s1 = __shfl(s, gb + 1);
            int s2 = __shfl(s, gb + 2);
            int off = (q > 0 ? s0 : 0) + (q > 1 ? s1 : 0) + (q > 2 ? s2 : 0);
#pragma unroll
            for (int j = 0; j < 16; j++)
                bcnt[(q * 16 + j) * N_NODES + n] = off + pre[j];
            if (q == 3) deg[n] = off + s;
        }
    }

    __threadfence();
    grid.sync();

    // ---------------- phase 3: single-pass scatter into padded CSR
    {
        const int i = bid * 256 + t;                   // 160000 < NTHR: single round
        if (i < N_EDGES / 4) {
            int b = i / (CHUNK / 4);                   // CHUNK%4==0: uint4 never straddles
            const int* pre = bcnt + b * N_NODES;
            uint4 p = ((const uint4*)pack)[i];
#pragma unroll
            for (int q = 0; q < 4; q++) {
                unsigned wd = (q == 0) ? p.x : (q == 1) ? p.y : (q == 2) ? p.z : p.w;
                int r = (int)((wd >> 14) & 0x3fffu);
                int s = (int)(wd & 0x3fffu);
                int l = (int)(wd >> 28);
                csr[(r << 8) + pre[r] + l] = s;
            }
        }
    }

    __threadfence();
    grid.sync();

    // ---------------- phase 4: reduction-free gather (16 lanes per node)
    {
        const int g = bid * 256 + t;                   // 160000 < NTHR: single round
        if (g < 16 * N_NODES) {
            const int n  = g >> 4;
            const int d4 = g & 15;

            const int dg   = deg[n];
            const int lim  = min(dg, PAD);
            const int base = n << 8;

            float acc[8];
#pragma unroll
            for (int k = 0; k < 8; k++) acc[k] = 0.f;

            const uint4* Y4 = (const uint4*)Yb;

            int j = 0;
            for (; j + 4 <= lim; j += 4) {
                int s0 = csr[base + j];
                int s1 = csr[base + j + 1];
                int s2 = csr[base + j + 2];
                int s3 = csr[base + j + 3];
                uint4 v0 = Y4[s0 * 16 + d4];
                uint4 v1 = Y4[s1 * 16 + d4];
                uint4 v2 = Y4[s2 * 16 + d4];
                uint4 v3 = Y4[s3 * 16 + d4];
                acc8(acc, v0);
                acc8(acc, v1);
                acc8(acc, v2);
                acc8(acc, v3);
            }
            for (; j < lim; j++) {
                int s = csr[base + j];
                acc8(acc, Y4[s * 16 + d4]);
            }

            const float inv = 1.0f / (float)max(dg, 1);
            float4 b0 = ((const float4*)bias)[d4 * 2];
            float4 b1 = ((const float4*)bias)[d4 * 2 + 1];
            float4 o0 = make_float4(acc[0] * inv + b0.x, acc[1] * inv + b0.y,
                                    acc[2] * inv + b0.z, acc[3] * inv + b0.w);
            float4 o1 = make_float4(acc[4] * inv + b1.x, acc[5] * inv + b1.y,
                                    acc[6] * inv + b1.z, acc[7] * inv + b1.w);
            ((float4*)&out[n * 128 + d4 * 8])[0] = o0;
            ((float4*)&out[n * 128 + d4 * 8])[1] = o1;
        }
    }
}

// ---------------------------------------------------------------------------
extern "C" void kernel_launch(void* const* d_in, const int* in_sizes, int n_in,
                              void* d_out, int out_size, void* d_ws, size_t ws_size,
                              hipStream_t stream) {
    const float* nodes     = (const float*)d_in[0];
    const int*   senders   = (const int*)  d_in[1];
    const int*   receivers = (const int*)  d_in[2];
    const float* Wm        = (const float*)d_in[3];
    const float* bias      = (const float*)d_in[4];
    float*       out       = (float*)d_out;

    // workspace layout (bytes)
    char*     w    = (char*)d_ws;
    unsigned* Yb   = (unsigned*)(w);               // bf16 Y:       2,560,000
    unsigned* pack = (unsigned*)(w + 2560000);     //               2,560,000
    int*      bcnt = (int*)(w + 5120000);          // 64x10000x4:   2,560,000
    int*      deg  = (int*)(w + 7680000);          //                  40,000
    int*      csr  = (int*)(w + 7720448);          // 10000x256x4: 10,240,000

    void* args[] = {(void*)&nodes, (void*)&Wm, (void*)&senders, (void*)&receivers,
                    (void*)&bias, (void*)&out, (void*)&Yb, (void*)&pack,
                    (void*)&bcnt, (void*)&deg, (void*)&csr};
    hipLaunchCooperativeKernel((const void*)mega_kernel, dim3(NBLK), dim3(256),
                               args, 0, stream);
}

// Round 6
// 403.838 us; speedup vs baseline: 1.5354x; 1.5354x over previous
//
#include <hip/hip_runtime.h>

#define N_NODES 10000
#define N_EDGES 640000
#define D       128

#define BUILD_BLOCKS 64                    // owner-pull CSR build blocks
#define NPB          157                   // nodes per build block (64*157=10048>=10000)
#define GEMM_BLOCKS  313                   // ceil(10000/32), 32-row M-tile
#define NBLK         (BUILD_BLOCKS + GEMM_BLOCKS)
#define PAD          256                   // padded CSR bucket (max deg ~64+6sd << 256)

// pack two fp32 -> two bf16 (RNE) in one uint (low = a, high = b)
__device__ inline unsigned bf16pair(float a, float b) {
    unsigned ua = __float_as_uint(a), ub = __float_as_uint(b);
    ua = (ua + 0x7fffu + ((ua >> 16) & 1u)) >> 16;
    ub = (ub + 0x7fffu + ((ub >> 16) & 1u)) >> 16;
    return ua | (ub << 16);
}

union FusedSmem {
    float As[32][132];    // gemm A-tile (16.9 KB)
    int   cnt[NPB];       // build counters (628 B)
};

__device__ inline void acc8(float* acc, uint4 v) {
    acc[0] += __uint_as_float(v.x << 16);
    acc[1] += __uint_as_float(v.x & 0xffff0000u);
    acc[2] += __uint_as_float(v.y << 16);
    acc[3] += __uint_as_float(v.y & 0xffff0000u);
    acc[4] += __uint_as_float(v.z << 16);
    acc[5] += __uint_as_float(v.z & 0xffff0000u);
    acc[6] += __uint_as_float(v.w << 16);
    acc[7] += __uint_as_float(v.w & 0xffff0000u);
}

// ---------------------------------------------------------------------------
// Kernel 1: blocks [0,64) -> owner-pull CSR build: block b owns receiver
// nodes [b*157, min(b*157+157,10000)). Scans ALL edges (5.12 MB, L2/L3-
// served; x64 blocks = 328 MB cache traffic ~ 10-15 us), keeps in-range
// edges via LDS counters -> csr/deg directly. Replaces hist+colscan+scatter
// (3 dispatches, pack/bcnt round-trips) with ONE pass, zero global atomics.
// Blocks [64,377) -> GEMM Y = nodes @ W -> bf16 (verified layout).
// R5 post-mortem: grid.sync() costs ~150us/barrier on gfx950 -> mega-kernel
// reverted; fixed per-iteration overhead ~71us measured, kernel sum is the
// only controllable budget (~41us in R0/R3 structure).
// ---------------------------------------------------------------------------
__global__ __launch_bounds__(256) void gemm_build_kernel(
    const float* __restrict__ nodes, const float* __restrict__ Wm,
    unsigned* __restrict__ Yb,
    const int* __restrict__ senders, const int* __restrict__ receivers,
    int* __restrict__ deg, int* __restrict__ csr)
{
    __shared__ FusedSmem sm;
    const int t = threadIdx.x;

    if (blockIdx.x < BUILD_BLOCKS) {
        const int lo = blockIdx.x * NPB;
        const int hi = min(lo + NPB, N_NODES);

        for (int i = t; i < NPB; i += 256) sm.cnt[i] = 0;
        __syncthreads();

        const int4* s4 = (const int4*)senders;
        const int4* r4 = (const int4*)receivers;
        // 160000 int4-pairs / 256 threads = 625 iters exactly
        for (int i = t; i < N_EDGES / 4; i += 256) {
            int4 r = r4[i];
            int4 s = s4[i];
            if (r.x >= lo && r.x < hi) {
                int l = atomicAdd(&sm.cnt[r.x - lo], 1);
                csr[(r.x << 8) + l] = s.x;
            }
            if (r.y >= lo && r.y < hi) {
                int l = atomicAdd(&sm.cnt[r.y - lo], 1);
                csr[(r.y << 8) + l] = s.y;
            }
            if (r.z >= lo && r.z < hi) {
                int l = atomicAdd(&sm.cnt[r.z - lo], 1);
                csr[(r.z << 8) + l] = s.z;
            }
            if (r.w >= lo && r.w < hi) {
                int l = atomicAdd(&sm.cnt[r.w - lo], 1);
                csr[(r.w << 8) + l] = s.w;
            }
        }
        __syncthreads();
        for (int i = t; lo + i < hi; i += 256) deg[lo + i] = sm.cnt[i];
    } else {
        const int row0 = (blockIdx.x - BUILD_BLOCKS) * 32;

        for (int i = t; i < 1024; i += 256) {
            int r  = i >> 5;
            int c  = i & 31;
            int gr = row0 + r;
            float4 v = make_float4(0.f, 0.f, 0.f, 0.f);
            if (gr < N_NODES) v = ((const float4*)nodes)[gr * 32 + c];
            *((float4*)&sm.As[r][c * 4]) = v;
        }
        __syncthreads();

        const int tx = t & 15;
        const int ty = t >> 4;
        const int r0 = ty * 2;

        float acc[2][8];
#pragma unroll
        for (int i = 0; i < 2; i++)
#pragma unroll
            for (int j = 0; j < 8; j++) acc[i][j] = 0.f;

        const float4* W4 = (const float4*)Wm;
#pragma unroll 4
        for (int k = 0; k < 128; k++) {
            float  a0 = sm.As[r0][k];
            float  a1 = sm.As[r0 + 1][k];
            float4 w0 = W4[k * 32 + tx * 2];
            float4 w1 = W4[k * 32 + tx * 2 + 1];
            float  wv[8] = {w0.x, w0.y, w0.z, w0.w, w1.x, w1.y, w1.z, w1.w};
#pragma unroll
            for (int j = 0; j < 8; j++) {
                acc[0][j] += a0 * wv[j];
                acc[1][j] += a1 * wv[j];
            }
        }

#pragma unroll
        for (int i = 0; i < 2; i++) {
            int gr = row0 + r0 + i;
            if (gr < N_NODES) {
                uint4 o;
                o.x = bf16pair(acc[i][0], acc[i][1]);
                o.y = bf16pair(acc[i][2], acc[i][3]);
                o.z = bf16pair(acc[i][4], acc[i][5]);
                o.w = bf16pair(acc[i][6], acc[i][7]);
                ((uint4*)Yb)[gr * 16 + tx] = o;        // 16 uint4 per 128-bf16 row
            }
        }
    }
}

// ---------------------------------------------------------------------------
// Kernel 2: reduction-free pull-gather (R3-verified). 16 lanes own one node
// (16 B of the 256 B bf16 row each); each lane iterates all edges of its
// node -> no LDS, no barriers, no reduction. Grid 625 x 256 = 10000 nodes.
// ---------------------------------------------------------------------------
__global__ __launch_bounds__(256) void gather_kernel(const unsigned* __restrict__ Yb,
                                                     const int* __restrict__ deg,
                                                     const int* __restrict__ csr,
                                                     const float* __restrict__ bias,
                                                     float* __restrict__ out) {
    const int t  = threadIdx.x;
    const int d4 = t & 15;                       // dim slot: 8 bf16 = 16 B
    const int n  = blockIdx.x * 16 + (t >> 4);   // grid = 625 -> exactly 10000

    const int dg   = deg[n];
    const int lim  = min(dg, PAD);
    const int base = n << 8;

    float acc[8];
#pragma unroll
    for (int k = 0; k < 8; k++) acc[k] = 0.f;

    const uint4* Y4 = (const uint4*)Yb;

    int j = 0;
    for (; j + 4 <= lim; j += 4) {
        int s0 = csr[base + j];
        int s1 = csr[base + j + 1];
        int s2 = csr[base + j + 2];
        int s3 = csr[base + j + 3];
        uint4 v0 = Y4[s0 * 16 + d4];
        uint4 v1 = Y4[s1 * 16 + d4];
        uint4 v2 = Y4[s2 * 16 + d4];
        uint4 v3 = Y4[s3 * 16 + d4];
        acc8(acc, v0);
        acc8(acc, v1);
        acc8(acc, v2);
        acc8(acc, v3);
    }
    for (; j < lim; j++) {
        int s = csr[base + j];
        acc8(acc, Y4[s * 16 + d4]);
    }

    const float inv = 1.0f / (float)max(dg, 1);
    float4 b0 = ((const float4*)bias)[d4 * 2];
    float4 b1 = ((const float4*)bias)[d4 * 2 + 1];
    float4 o0 = make_float4(acc[0] * inv + b0.x, acc[1] * inv + b0.y,
                            acc[2] * inv + b0.z, acc[3] * inv + b0.w);
    float4 o1 = make_float4(acc[4] * inv + b1.x, acc[5] * inv + b1.y,
                            acc[6] * inv + b1.z, acc[7] * inv + b1.w);
    ((float4*)&out[n * 128 + d4 * 8])[0] = o0;
    ((float4*)&out[n * 128 + d4 * 8])[1] = o1;
}

// ---------------------------------------------------------------------------
extern "C" void kernel_launch(void* const* d_in, const int* in_sizes, int n_in,
                              void* d_out, int out_size, void* d_ws, size_t ws_size,
                              hipStream_t stream) {
    const float* nodes     = (const float*)d_in[0];
    const int*   senders   = (const int*)  d_in[1];
    const int*   receivers = (const int*)  d_in[2];
    const float* Wm        = (const float*)d_in[3];
    const float* bias      = (const float*)d_in[4];
    float*       out       = (float*)d_out;

    // workspace layout (bytes)
    char*     w   = (char*)d_ws;
    unsigned* Yb  = (unsigned*)(w);                // bf16 Y:       2,560,000
    int*      deg = (int*)(w + 2560000);           //                  40,000
    int*      csr = (int*)(w + 2600192);           // 10000x256x4: 10,240,000

    gemm_build_kernel<<<NBLK, 256, 0, stream>>>(nodes, Wm, Yb, senders,
                                                receivers, deg, csr);
    gather_kernel<<<(N_NODES + 15) / 16, 256, 0, stream>>>(Yb, deg, csr, bias, out);
}

// Round 7
// 119.831 us; speedup vs baseline: 5.1744x; 3.3701x over previous
//
#include <hip/hip_runtime.h>

#define N_NODES 10000
#define N_EDGES 640000
#define D       128

#define HB          64             // localhist chunks
#define GEMM_BLOCKS 625            // 10000/16 exactly, 16-row M-tile
#define CHUNK       10000          // edges per chunk (64*10000 = 640000)
#define PAD         256            // padded CSR bucket (max deg ~64+6sd << 256)
#define GROUPS      8              // XCD partitioning for scatter
#define NODES_PER_GROUP 1250
#define SBPG        128            // scatter blocks per group -> 1024 total

// pack two fp32 -> two bf16 (RNE) in one uint (low = a, high = b)
__device__ inline unsigned bf16pair(float a, float b) {
    unsigned ua = __float_as_uint(a), ub = __float_as_uint(b);
    ua = (ua + 0x7fffu + ((ua >> 16) & 1u)) >> 16;
    ub = (ub + 0x7fffu + ((ub >> 16) & 1u)) >> 16;
    return ua | (ub << 16);
}

union FusedSmem {
    float    As[16][132];          // gemm A-tile (8.4 KB)
    unsigned cnt2[N_NODES / 2];    // hist counters, 2x16-bit per word (20 KB)
};
// union max = 20 KB -> 8 blocks/CU LDS cap (R0's 40 KB union capped at 4:
// that was the GEMM's hidden occupancy killer).

__device__ inline void acc8(float* acc, uint4 v) {
    acc[0] += __uint_as_float(v.x << 16);
    acc[1] += __uint_as_float(v.x & 0xffff0000u);
    acc[2] += __uint_as_float(v.y << 16);
    acc[3] += __uint_as_float(v.y & 0xffff0000u);
    acc[4] += __uint_as_float(v.z << 16);
    acc[5] += __uint_as_float(v.z & 0xffff0000u);
    acc[6] += __uint_as_float(v.w << 16);
    acc[7] += __uint_as_float(v.w & 0xffff0000u);
}

// ---------------------------------------------------------------------------
// Kernel 1 (fused): blocks [0,64) -> LDS local histogram + edge packing
// (16-bit packed counters: per-chunk per-node count ~Poisson(1), max ~9 << 2^16,
// carry never crosses fields). pack[e] = s(14b) | r(14b)<<14 | lrank(4b)<<28.
// Blocks [64,689) -> Y = nodes @ W -> bf16. 16-row tile, 1 row x 8 cols per
// thread: 2x the blocks + half the LDS of R0 -> ~2.5 waves/SIMD (was 1.2).
// R6 post-mortem: owner-pull build (64 blocks x full edge scan) was 330 us,
// latency-bound with zero TLP. Reverted to R0's chunked hist build.
// ---------------------------------------------------------------------------
__global__ __launch_bounds__(256) void gemm_hist_kernel(const float* __restrict__ nodes,
                                                        const float* __restrict__ Wm,
                                                        unsigned* __restrict__ Yb,
                                                        const int* __restrict__ senders,
                                                        const int* __restrict__ receivers,
                                                        unsigned* __restrict__ pack,
                                                        int* __restrict__ bcnt) {
    __shared__ FusedSmem sm;
    const int t = threadIdx.x;

    if (blockIdx.x < HB) {
        const int b = blockIdx.x;
        for (int n = t; n < N_NODES / 2; n += 256) sm.cnt2[n] = 0;
        __syncthreads();
        const int base = b * CHUNK;
        for (int i = t; i < CHUNK; i += 256) {
            int r = receivers[base + i];
            int s = senders[base + i];
            unsigned sh  = (unsigned)(r & 1) * 16u;
            unsigned old = atomicAdd(&sm.cnt2[r >> 1], 1u << sh);   // LDS atomic
            unsigned l   = (old >> sh) & 0xffffu;
            pack[base + i] = (unsigned)s | ((unsigned)r << 14) | (l << 28);
        }
        __syncthreads();
        int* dst = bcnt + b * N_NODES;
        for (int n = t; n < N_NODES; n += 256)
            dst[n] = (int)((sm.cnt2[n >> 1] >> ((unsigned)(n & 1) * 16u)) & 0xffffu);
    } else {
        const int row0 = (blockIdx.x - HB) * 16;       // 625*16 = 10000 exact

        for (int i = t; i < 512; i += 256) {           // 16 rows x 32 float4
            int r = i >> 5;
            int c = i & 31;
            *((float4*)&sm.As[r][c * 4]) = ((const float4*)nodes)[(row0 + r) * 32 + c];
        }
        __syncthreads();

        const int tx  = t & 15;
        const int ty  = t >> 4;                        // 0..15: one row per thread
        const int row = row0 + ty;

        float acc[8];
#pragma unroll
        for (int j = 0; j < 8; j++) acc[j] = 0.f;

        const float4* W4 = (const float4*)Wm;
#pragma unroll 4
        for (int k = 0; k < 128; k++) {
            float  a0 = sm.As[ty][k];
            float4 w0 = W4[k * 32 + tx * 2];
            float4 w1 = W4[k * 32 + tx * 2 + 1];
            acc[0] += a0 * w0.x;
            acc[1] += a0 * w0.y;
            acc[2] += a0 * w0.z;
            acc[3] += a0 * w0.w;
            acc[4] += a0 * w1.x;
            acc[5] += a0 * w1.y;
            acc[6] += a0 * w1.z;
            acc[7] += a0 * w1.w;
        }

        uint4 o;
        o.x = bf16pair(acc[0], acc[1]);
        o.y = bf16pair(acc[2], acc[3]);
        o.z = bf16pair(acc[4], acc[5]);
        o.w = bf16pair(acc[6], acc[7]);
        ((uint4*)Yb)[row * 16 + tx] = o;               // 16 uint4 per 128-bf16 row
    }
}

// ---------------------------------------------------------------------------
// Kernel 2: column scan, 4 threads per node (R0-verified).
// ---------------------------------------------------------------------------
__global__ __launch_bounds__(256) void colscan_kernel(int* __restrict__ bcnt,
                                                      int* __restrict__ deg) {
    const int g = blockIdx.x * 256 + threadIdx.x;
    const int n = g >> 2;
    const int q = g & 3;
    if (n >= N_NODES) return;

    int pre[16];
    int s = 0;
#pragma unroll
    for (int j = 0; j < 16; j++) {
        int v = bcnt[(q * 16 + j) * N_NODES + n];
        pre[j] = s;
        s += v;
    }

    const int lane = threadIdx.x & 63;
    const int gb   = lane & ~3;
    int s0 = __shfl(s, gb + 0);
    int s1 = __shfl(s, gb + 1);
    int s2 = __shfl(s, gb + 2);
    int off = (q > 0 ? s0 : 0) + (q > 1 ? s1 : 0) + (q > 2 ? s2 : 0);

#pragma unroll
    for (int j = 0; j < 16; j++)
        bcnt[(q * 16 + j) * N_NODES + n] = off + pre[j];
    if (q == 3) deg[n] = off + s;
}

// ---------------------------------------------------------------------------
// Kernel 3: XCD-partitioned scatter into padded CSR — atomic-free (R0-verified).
// ---------------------------------------------------------------------------
__global__ __launch_bounds__(256) void scatter_kernel(const unsigned* __restrict__ pack,
                                                      const int* __restrict__ bcnt,
                                                      int* __restrict__ csr) {
    const int x  = blockIdx.x & 7;
    const int bg = blockIdx.x >> 3;
    const int lo = x * NODES_PER_GROUP;
    const int hi = lo + NODES_PER_GROUP;

    for (int i = bg * 256 + threadIdx.x; i < N_EDGES / 4; i += SBPG * 256) {
        int b = i / (CHUNK / 4);              // CHUNK%4==0: uint4 never straddles
        const int* pre = bcnt + b * N_NODES;
        uint4 p = ((const uint4*)pack)[i];
#pragma unroll
        for (int q = 0; q < 4; q++) {
            unsigned wd = (q == 0) ? p.x : (q == 1) ? p.y : (q == 2) ? p.z : p.w;
            int r = (int)((wd >> 14) & 0x3fffu);
            if (r >= lo && r < hi) {
                int s = (int)(wd & 0x3fffu);
                int l = (int)(wd >> 28);
                csr[(r << 8) + pre[r] + l] = s;
            }
        }
    }
}

// ---------------------------------------------------------------------------
// Kernel 4: reduction-free pull-gather (R3-verified). 16 lanes per node.
// ---------------------------------------------------------------------------
__global__ __launch_bounds__(256) void gather_kernel(const unsigned* __restrict__ Yb,
                                                     const int* __restrict__ deg,
                                                     const int* __restrict__ csr,
                                                     const float* __restrict__ bias,
                                                     float* __restrict__ out) {
    const int t  = threadIdx.x;
    const int d4 = t & 15;
    const int n  = blockIdx.x * 16 + (t >> 4);   // grid = 625 -> exactly 10000

    const int dg   = deg[n];
    const int lim  = min(dg, PAD);
    const int base = n << 8;

    float acc[8];
#pragma unroll
    for (int k = 0; k < 8; k++) acc[k] = 0.f;

    const uint4* Y4 = (const uint4*)Yb;

    int j = 0;
    for (; j + 4 <= lim; j += 4) {
        int s0 = csr[base + j];
        int s1 = csr[base + j + 1];
        int s2 = csr[base + j + 2];
        int s3 = csr[base + j + 3];
        uint4 v0 = Y4[s0 * 16 + d4];
        uint4 v1 = Y4[s1 * 16 + d4];
        uint4 v2 = Y4[s2 * 16 + d4];
        uint4 v3 = Y4[s3 * 16 + d4];
        acc8(acc, v0);
        acc8(acc, v1);
        acc8(acc, v2);
        acc8(acc, v3);
    }
    for (; j < lim; j++) {
        int s = csr[base + j];
        acc8(acc, Y4[s * 16 + d4]);
    }

    const float inv = 1.0f / (float)max(dg, 1);
    float4 b0 = ((const float4*)bias)[d4 * 2];
    float4 b1 = ((const float4*)bias)[d4 * 2 + 1];
    float4 o0 = make_float4(acc[0] * inv + b0.x, acc[1] * inv + b0.y,
                            acc[2] * inv + b0.z, acc[3] * inv + b0.w);
    float4 o1 = make_float4(acc[4] * inv + b1.x, acc[5] * inv + b1.y,
                            acc[6] * inv + b1.z, acc[7] * inv + b1.w);
    ((float4*)&out[n * 128 + d4 * 8])[0] = o0;
    ((float4*)&out[n * 128 + d4 * 8])[1] = o1;
}

// ---------------------------------------------------------------------------
extern "C" void kernel_launch(void* const* d_in, const int* in_sizes, int n_in,
                              void* d_out, int out_size, void* d_ws, size_t ws_size,
                              hipStream_t stream) {
    const float* nodes     = (const float*)d_in[0];
    const int*   senders   = (const int*)  d_in[1];
    const int*   receivers = (const int*)  d_in[2];
    const float* Wm        = (const float*)d_in[3];
    const float* bias      = (const float*)d_in[4];
    float*       out       = (float*)d_out;

    // workspace layout (bytes)
    char*     w    = (char*)d_ws;
    unsigned* Yb   = (unsigned*)(w);               // bf16 Y:       2,560,000
    unsigned* pack = (unsigned*)(w + 2560000);     //               2,560,000
    int*      bcnt = (int*)(w + 5120000);          // 64x10000x4:   2,560,000
    int*      deg  = (int*)(w + 7680000);          //                  40,000
    int*      csr  = (int*)(w + 7720448);          // 10000x256x4: 10,240,000

    gemm_hist_kernel<<<HB + GEMM_BLOCKS, 256, 0, stream>>>(nodes, Wm, Yb,
                                                           senders, receivers,
                                                           pack, bcnt);
    colscan_kernel  <<<(4 * N_NODES + 255) / 256, 256, 0, stream>>>(bcnt, deg);
    scatter_kernel  <<<GROUPS * SBPG, 256, 0, stream>>>(pack, bcnt, csr);
    gather_kernel   <<<(N_NODES + 15) / 16, 256, 0, stream>>>(Yb, deg, csr, bias, out);
}

// Round 8
// 114.180 us; speedup vs baseline: 5.4305x; 1.0495x over previous
//
#include <hip/hip_runtime.h>

#define N_NODES 10000
#define N_EDGES 640000
#define D       128

#define GEMM_BLOCKS 313            // ceil(10000/32), 32-row M-tile (conflict-free banks)
#define HB          64             // localhist chunks
#define CHUNK       10000          // edges per chunk (64*10000 = 640000)
#define PAD         256            // padded CSR bucket (max deg ~64+6sd << 256)

// pack two fp32 -> two bf16 (RNE) in one uint (low = a, high = b)
__device__ inline unsigned bf16pair(float a, float b) {
    unsigned ua = __float_as_uint(a), ub = __float_as_uint(b);
    ua = (ua + 0x7fffu + ((ua >> 16) & 1u)) >> 16;
    ub = (ub + 0x7fffu + ((ub >> 16) & 1u)) >> 16;
    return ua | (ub << 16);
}

union FusedSmem {
    float As[32][132];    // gemm A-tile (16.9 KB); r0=2*ty -> banks k,k+8,k+16,k+24: conflict-free
    int   cnt[N_NODES];   // hist counters (40 KB)
};

// ---------------------------------------------------------------------------
// Kernel 1 (fused): blocks [0,313) -> Y = nodes @ W stored bf16 — EXACT R0
// form (32-row tile, 2 rows x 8 cols/thread). R7 post-mortem: 16-row tile
// regressed +8us — GEMM is W-fetch-bound per thread, not occupancy-bound
// (halving rows/thread doubled W traffic per FLOP). Do not shrink the tile.
// Blocks [313,377) -> LDS local histogram + packing.
// pack[e] = sender(14b) | receiver(14b)<<14 | lrank(4b)<<28.
// ---------------------------------------------------------------------------
__global__ __launch_bounds__(256) void gemm_hist_kernel(const float* __restrict__ nodes,
                                                        const float* __restrict__ Wm,
                                                        unsigned* __restrict__ Yb,
                                                        const int* __restrict__ senders,
                                                        const int* __restrict__ receivers,
                                                        unsigned* __restrict__ pack,
                                                        int* __restrict__ bcnt) {
    __shared__ FusedSmem sm;
    const int t = threadIdx.x;

    if (blockIdx.x < GEMM_BLOCKS) {
        const int row0 = blockIdx.x * 32;

        for (int i = t; i < 1024; i += 256) {
            int r  = i >> 5;
            int c  = i & 31;
            int gr = row0 + r;
            float4 v = make_float4(0.f, 0.f, 0.f, 0.f);
            if (gr < N_NODES) v = ((const float4*)nodes)[gr * 32 + c];
            *((float4*)&sm.As[r][c * 4]) = v;
        }
        __syncthreads();

        const int tx = t & 15;
        const int ty = t >> 4;
        const int c0 = tx * 8;
        const int r0 = ty * 2;

        float acc[2][8];
#pragma unroll
        for (int i = 0; i < 2; i++)
#pragma unroll
            for (int j = 0; j < 8; j++) acc[i][j] = 0.f;

        const float4* W4 = (const float4*)Wm;
#pragma unroll 4
        for (int k = 0; k < 128; k++) {
            float  a0 = sm.As[r0][k];
            float  a1 = sm.As[r0 + 1][k];
            float4 w0 = W4[k * 32 + tx * 2];
            float4 w1 = W4[k * 32 + tx * 2 + 1];
            float  wv[8] = {w0.x, w0.y, w0.z, w0.w, w1.x, w1.y, w1.z, w1.w};
#pragma unroll
            for (int j = 0; j < 8; j++) {
                acc[0][j] += a0 * wv[j];
                acc[1][j] += a1 * wv[j];
            }
        }

#pragma unroll
        for (int i = 0; i < 2; i++) {
            int gr = row0 + r0 + i;
            if (gr < N_NODES) {
                uint4 o;
                o.x = bf16pair(acc[i][0], acc[i][1]);
                o.y = bf16pair(acc[i][2], acc[i][3]);
                o.z = bf16pair(acc[i][4], acc[i][5]);
                o.w = bf16pair(acc[i][6], acc[i][7]);
                ((uint4*)Yb)[gr * 16 + (c0 >> 3)] = o;
            }
        }
    } else {
        const int b = blockIdx.x - GEMM_BLOCKS;
        for (int n = t; n < N_NODES; n += 256) sm.cnt[n] = 0;
        __syncthreads();
        const int base = b * CHUNK;
        for (int i = t; i < CHUNK; i += 256) {
            int r = receivers[base + i];
            int s = senders[base + i];
            int l = atomicAdd(&sm.cnt[r], 1);          // LDS atomic: ns-latency
            pack[base + i] = (unsigned)s | ((unsigned)r << 14) | ((unsigned)l << 28);
        }
        __syncthreads();
        int* dst = bcnt + b * N_NODES;
        for (int n = t; n < N_NODES; n += 256) dst[n] = sm.cnt[n];
    }
}

// ---------------------------------------------------------------------------
// Kernel 2: column scan, 4 threads per node (R0-verified).
// ---------------------------------------------------------------------------
__global__ __launch_bounds__(256) void colscan_kernel(int* __restrict__ bcnt,
                                                      int* __restrict__ deg) {
    const int g = blockIdx.x * 256 + threadIdx.x;
    const int n = g >> 2;
    const int q = g & 3;
    if (n >= N_NODES) return;

    int pre[16];
    int s = 0;
#pragma unroll
    for (int j = 0; j < 16; j++) {
        int v = bcnt[(q * 16 + j) * N_NODES + n];
        pre[j] = s;
        s += v;
    }

    const int lane = threadIdx.x & 63;
    const int gb   = lane & ~3;          // group base lane
    int s0 = __shfl(s, gb + 0);
    int s1 = __shfl(s, gb + 1);
    int s2 = __shfl(s, gb + 2);
    int off = (q > 0 ? s0 : 0) + (q > 1 ? s1 : 0) + (q > 2 ? s2 : 0);

#pragma unroll
    for (int j = 0; j < 16; j++)
        bcnt[(q * 16 + j) * N_NODES + n] = off + pre[j];
    if (q == 3) deg[n] = off + s;
}

// ---------------------------------------------------------------------------
// Kernel 3: SINGLE-PASS scatter into padded CSR (form validated in R5's
// mega-kernel phase 3). Replaces the 8-group XCD-partitioned version: that
// read pack 8x (20 MB) + 5.1M range predicates to make 2.5 MB of writes
// XCD-local — the insurance cost more than the hazard. Each thread: one
// uint4 of pack, 4 bcnt gathers, 4 scattered csr stores. Grid = 625 exact.
// ---------------------------------------------------------------------------
__global__ __launch_bounds__(256) void scatter_kernel(const unsigned* __restrict__ pack,
                                                      const int* __restrict__ bcnt,
                                                      int* __restrict__ csr) {
    const int i = blockIdx.x * 256 + threadIdx.x;    // 160000 uint4s exactly
    if (i >= N_EDGES / 4) return;
    const int b = i / (CHUNK / 4);                   // CHUNK%4==0: uint4 never straddles
    const int* pre = bcnt + b * N_NODES;
    uint4 p = ((const uint4*)pack)[i];
#pragma unroll
    for (int q = 0; q < 4; q++) {
        unsigned wd = (q == 0) ? p.x : (q == 1) ? p.y : (q == 2) ? p.z : p.w;
        int r = (int)((wd >> 14) & 0x3fffu);
        int s = (int)(wd & 0x3fffu);
        int l = (int)(wd >> 28);
        csr[(r << 8) + pre[r] + l] = s;
    }
}

// ---------------------------------------------------------------------------
// Kernel 4: reduction-free pull-gather (R3-verified). 16 lanes own one node
// (16 B of the 256 B bf16 row each); no LDS, no barriers, no reduction.
// ---------------------------------------------------------------------------
__device__ inline void acc8(float* acc, uint4 v) {
    acc[0] += __uint_as_float(v.x << 16);
    acc[1] += __uint_as_float(v.x & 0xffff0000u);
    acc[2] += __uint_as_float(v.y << 16);
    acc[3] += __uint_as_float(v.y & 0xffff0000u);
    acc[4] += __uint_as_float(v.z << 16);
    acc[5] += __uint_as_float(v.z & 0xffff0000u);
    acc[6] += __uint_as_float(v.w << 16);
    acc[7] += __uint_as_float(v.w & 0xffff0000u);
}

__global__ __launch_bounds__(256) void gather_kernel(const unsigned* __restrict__ Yb,
                                                     const int* __restrict__ deg,
                                                     const int* __restrict__ csr,
                                                     const float* __restrict__ bias,
                                                     float* __restrict__ out) {
    const int t  = threadIdx.x;
    const int d4 = t & 15;                       // dim slot: 8 bf16 = 16 B
    const int n  = blockIdx.x * 16 + (t >> 4);   // grid = 625 -> exactly 10000

    const int dg   = deg[n];
    const int lim  = min(dg, PAD);
    const int base = n << 8;

    float acc[8];
#pragma unroll
    for (int k = 0; k < 8; k++) acc[k] = 0.f;

    const uint4* Y4 = (const uint4*)Yb;

    int j = 0;
    for (; j + 4 <= lim; j += 4) {
        int s0 = csr[base + j];
        int s1 = csr[base + j + 1];
        int s2 = csr[base + j + 2];
        int s3 = csr[base + j + 3];
        uint4 v0 = Y4[s0 * 16 + d4];
        uint4 v1 = Y4[s1 * 16 + d4];
        uint4 v2 = Y4[s2 * 16 + d4];
        uint4 v3 = Y4[s3 * 16 + d4];
        acc8(acc, v0);
        acc8(acc, v1);
        acc8(acc, v2);
        acc8(acc, v3);
    }
    for (; j < lim; j++) {
        int s = csr[base + j];
        acc8(acc, Y4[s * 16 + d4]);
    }

    const float inv = 1.0f / (float)max(dg, 1);
    float4 b0 = ((const float4*)bias)[d4 * 2];
    float4 b1 = ((const float4*)bias)[d4 * 2 + 1];
    float4 o0 = make_float4(acc[0] * inv + b0.x, acc[1] * inv + b0.y,
                            acc[2] * inv + b0.z, acc[3] * inv + b0.w);
    float4 o1 = make_float4(acc[4] * inv + b1.x, acc[5] * inv + b1.y,
                            acc[6] * inv + b1.z, acc[7] * inv + b1.w);
    ((float4*)&out[n * 128 + d4 * 8])[0] = o0;
    ((float4*)&out[n * 128 + d4 * 8])[1] = o1;
}

// ---------------------------------------------------------------------------
extern "C" void kernel_launch(void* const* d_in, const int* in_sizes, int n_in,
                              void* d_out, int out_size, void* d_ws, size_t ws_size,
                              hipStream_t stream) {
    const float* nodes     = (const float*)d_in[0];
    const int*   senders   = (const int*)  d_in[1];
    const int*   receivers = (const int*)  d_in[2];
    const float* Wm        = (const float*)d_in[3];
    const float* bias      = (const float*)d_in[4];
    float*       out       = (float*)d_out;

    // workspace layout (bytes)
    char*     w    = (char*)d_ws;
    unsigned* Yb   = (unsigned*)(w);               // bf16 Y:       2,560,000
    unsigned* pack = (unsigned*)(w + 2560000);     //               2,560,000
    int*      bcnt = (int*)(w + 5120000);          // 64x10000x4:   2,560,000
    int*      deg  = (int*)(w + 7680000);          //                  40,000
    int*      csr  = (int*)(w + 7720448);          // 10000x256x4: 10,240,000

    gemm_hist_kernel<<<GEMM_BLOCKS + HB, 256, 0, stream>>>(nodes, Wm, Yb,
                                                           senders, receivers,
                                                           pack, bcnt);
    colscan_kernel  <<<(4 * N_NODES + 255) / 256, 256, 0, stream>>>(bcnt, deg);
    scatter_kernel  <<<(N_EDGES / 4 + 255) / 256, 256, 0, stream>>>(pack, bcnt, csr);
    gather_kernel   <<<(N_NODES + 15) / 16, 256, 0, stream>>>(Yb, deg, csr, bias, out);
}